// Round 9
// baseline (76.132 us; speedup 1.0000x reference)
//
#include <hip/hip_runtime.h>
#include <cstddef>
#include <cstdint>

// Problem constants: T=2048, B=8, C=1024, H=16, K=31, P=15
constexpr int T_ = 2048;
constexpr int B_ = 8;
constexpr int C_ = 1024;
constexpr int H_ = 16;
constexpr int K_ = 31;
constexpr int P_ = 15;
constexpr int M_ = T_ * B_;   // 16384
constexpr int N_ = H_ * K_;   // 496
constexpr int NP = 512;       // padded N, slot layout n' = h*32 + k

typedef _Float16 f16x4 __attribute__((ext_vector_type(4)));
typedef _Float16 f16x8 __attribute__((ext_vector_type(8)));
typedef float f32x4 __attribute__((ext_vector_type(4)));

__device__ __forceinline__ void async_cp16(const void* g, void* l) {
    __builtin_amdgcn_global_load_lds(
        (const __attribute__((address_space(1))) void*)g,
        (__attribute__((address_space(3))) void*)l, 16, 0, 0);
}

// ---------------------------------------------------------------------------
// K0: fused convert. X -> Xh fp16; W -> Wh (512x1024 fp16, slot layout
// n' = h*32+k; k==31 rows zero). Unchanged from round 8.
// ---------------------------------------------------------------------------
constexpr int XCH = M_ * C_ / 8;    // 2,097,152 f16x8 chunks
constexpr int WCH = NP * C_ / 8;    // 65,536

__global__ __launch_bounds__(256)
void cvt_inputs(const float* __restrict__ X, const float* __restrict__ W,
                _Float16* __restrict__ Xh, _Float16* __restrict__ Wh) {
    const int id = blockIdx.x * 256 + threadIdx.x;
    if (id < XCH) {
        const float4 v0 = *(const float4*)(X + (size_t)id * 8);
        const float4 v1 = *(const float4*)(X + (size_t)id * 8 + 4);
        f16x8 hv;
        hv[0] = (_Float16)v0.x; hv[1] = (_Float16)v0.y;
        hv[2] = (_Float16)v0.z; hv[3] = (_Float16)v0.w;
        hv[4] = (_Float16)v1.x; hv[5] = (_Float16)v1.y;
        hv[6] = (_Float16)v1.z; hv[7] = (_Float16)v1.w;
        *(f16x8*)(Xh + (size_t)id * 8) = hv;
    } else {
        const int j = id - XCH;
        const int n = j >> 7, sp = j & 127;
        const int h = n >> 5, k = n & 31;
        f16x8 hv = {};
        if (k < 31) {
            const float* wp = W + (size_t)(h * 31 + k) * C_ + sp * 8;
            const float4 v0 = *(const float4*)(wp);
            const float4 v1 = *(const float4*)(wp + 4);
            hv[0] = (_Float16)v0.x; hv[1] = (_Float16)v0.y;
            hv[2] = (_Float16)v0.z; hv[3] = (_Float16)v0.w;
            hv[4] = (_Float16)v1.x; hv[5] = (_Float16)v1.y;
            hv[6] = (_Float16)v1.z; hv[7] = (_Float16)v1.w;
        }
        *(f16x8*)(Wh + (size_t)n * C_ + sp * 8) = hv;
    }
}

// ---------------------------------------------------------------------------
// K1: fully fused GEMM + softmax + depthwise dynamic conv.
// Grid (128, 4): block = (16 t x 8 b) x 4 heads. 256 threads, 80 KB LDS
// (2 blocks/CU). Phases:
//  1. GEMM (round-8 structure: counted vmcnt, A 3-deep, B 2-deep).
//  2. logits -> Ls overlay (A region); softmax -> Wls fp16 (B region).
//  3. conv: 8 iters (head x b-half): stage xs (46t x 4b x 64ch f16->f32,
//     swizzled, A region), dconv inner loop, write out directly.
// ---------------------------------------------------------------------------
__global__ __launch_bounds__(256)
void fused_gsc(const _Float16* __restrict__ Xh, const _Float16* __restrict__ Wh,
               float* __restrict__ out) {
    __shared__ __align__(16) char smem[81920];
    _Float16* const As = (_Float16*)smem;              // 3 x 8192 halves, 48 KB
    _Float16* const Bs = (_Float16*)(smem + 49152);    // 2 x 8192 halves, 32 KB
    _Float16* const Ls = (_Float16*)smem;              // 128x136, 34.8 KB (A ovl)
    _Float16* const Wls = (_Float16*)(smem + 49152);   // 4x128x32, 32 KB (B ovl)
    float (* const xs)[64] = (float(*)[64])smem;       // 184x64 f32, 47 KB (A ovl)

    const int tid = threadIdx.x;
    const int lane = tid & 63;
    const int w = tid >> 6;
    const int wm = (w >> 1) * 64;
    const int wn = (w & 1) * 64;
    const int col = lane & 15;
    const int g = lane >> 4;
    const int m0 = blockIdx.x * 128;
    const int n0 = blockIdx.y * 128;

    // ---------------- phase 1: GEMM ----------------
    const _Float16* asrc[4];
    const _Float16* bsrc[4];
#pragma unroll
    for (int p = 0; p < 4; ++p) {
        const int ci = p * 256 + tid;
        const int r = ci >> 3, cs = ci & 7;
        const int cl = cs ^ (r & 7);
        asrc[p] = Xh + (size_t)(m0 + r) * C_ + cl * 8;
        bsrc[p] = Wh + (size_t)(n0 + r) * C_ + cl * 8;
    }

    f32x4 acc[4][4] = {};

#pragma unroll
    for (int p = 0; p < 4; ++p) {
        const int ci = p * 256 + tid;
        async_cp16(asrc[p], As + ci * 8);
    }
#pragma unroll
    for (int p = 0; p < 4; ++p) {
        const int ci = p * 256 + tid;
        async_cp16(bsrc[p], Bs + ci * 8);
    }
#pragma unroll
    for (int p = 0; p < 4; ++p) {
        const int ci = p * 256 + tid;
        async_cp16(asrc[p] + 64, As + 8192 + ci * 8);
    }
    asm volatile("s_waitcnt vmcnt(4)" ::: "memory");
    __builtin_amdgcn_s_barrier();
    __builtin_amdgcn_sched_barrier(0);

    for (int t = 0; t < 16; ++t) {
        const int ca = t % 3, cb = t & 1;
        if (t < 15) {
            const int k1 = (t + 1) * 64;
#pragma unroll
            for (int p = 0; p < 4; ++p) {
                const int ci = p * 256 + tid;
                async_cp16(bsrc[p] + k1, Bs + (cb ^ 1) * 8192 + ci * 8);
            }
        }
        if (t < 14) {
            const int k2 = (t + 2) * 64;
            const int ca2 = (t + 2) % 3;
#pragma unroll
            for (int p = 0; p < 4; ++p) {
                const int ci = p * 256 + tid;
                async_cp16(asrc[p] + k2, As + ca2 * 8192 + ci * 8);
            }
        }

        f16x8 a[2][4], b[2][4];
#pragma unroll
        for (int kk = 0; kk < 2; ++kk) {
#pragma unroll
            for (int mf = 0; mf < 4; ++mf) {
                const int row = wm + mf * 16 + col;
                const int c = ((kk << 2) | g) ^ (row & 7);
                a[kk][mf] = *(const f16x8*)&As[ca * 8192 + row * 64 + c * 8];
            }
#pragma unroll
            for (int nf = 0; nf < 4; ++nf) {
                const int row = wn + nf * 16 + col;
                const int c = ((kk << 2) | g) ^ (row & 7);
                b[kk][nf] = *(const f16x8*)&Bs[cb * 8192 + row * 64 + c * 8];
            }
        }
#pragma unroll
        for (int kk = 0; kk < 2; ++kk)
#pragma unroll
            for (int nf = 0; nf < 4; ++nf)
#pragma unroll
                for (int mf = 0; mf < 4; ++mf)
                    acc[mf][nf] = __builtin_amdgcn_mfma_f32_16x16x32_f16(
                        a[kk][mf], b[kk][nf], acc[mf][nf], 0, 0, 0);

        if (t < 14) {
            asm volatile("s_waitcnt vmcnt(4)" ::: "memory");
        } else {
            asm volatile("s_waitcnt vmcnt(0)" ::: "memory");
        }
        __builtin_amdgcn_s_barrier();
        __builtin_amdgcn_sched_barrier(0);
    }

    // ---------------- phase 2: logits -> Ls; softmax -> Wls ----------------
    const int rb = g * 4;
#pragma unroll
    for (int nf = 0; nf < 4; ++nf) {
        const int nl = wn + nf * 16 + col;
#pragma unroll
        for (int mf = 0; mf < 4; ++mf) {
            const int row = wm + mf * 16 + rb;
#pragma unroll
            for (int r = 0; r < 4; ++r)
                Ls[(row + r) * 136 + nl] = (_Float16)acc[mf][nf][r];
        }
    }
    __syncthreads();

#pragma unroll
    for (int p = 0; p < 2; ++p) {
        const int task = tid + p * 256;
        const int row = task >> 2, hl = task & 3;
        const _Float16* lp = &Ls[row * 136 + hl * 32];
        float v[32];
#pragma unroll
        for (int c = 0; c < 4; ++c) {
            const f16x8 ch = *(const f16x8*)(lp + c * 8);
#pragma unroll
            for (int e = 0; e < 8; ++e) v[c * 8 + e] = (float)ch[e];
        }
        float mx = v[0];
#pragma unroll
        for (int k = 1; k < 31; ++k) mx = fmaxf(mx, v[k]);
        float ssum = 0.f;
#pragma unroll
        for (int k = 0; k < 31; ++k) { v[k] = __expf(v[k] - mx); ssum += v[k]; }
        const float inv = 1.f / ssum;
        _Float16* op = &Wls[(hl * 128 + row) * 32];
#pragma unroll
        for (int c = 0; c < 4; ++c) {
            f16x8 ov;
#pragma unroll
            for (int e = 0; e < 8; ++e) {
                const int k = c * 8 + e;
                ov[e] = (k < 31) ? (_Float16)(v[k] * inv) : (_Float16)0.f;
            }
            *(f16x8*)(op + c * 8) = ov;
        }
    }

    // ---------------- phase 3: conv ----------------
    const int t0 = blockIdx.x * 16;
    const int hbase = blockIdx.y * 4;
    const int s = tid & 15;
    const int grp = tid >> 4;
    const int bl = grp & 3;
    const int tquad = (grp >> 2) * 4;

    for (int iter = 0; iter < 8; ++iter) {
        const int hl = iter >> 1, bh = iter & 1;
        const int h = hbase + hl;
        __syncthreads();   // xs region free (softmax Ls reads / prev compute done)

        // stage xs: 46 t x 4 b rows x 64 ch, f16 -> f32, chunk-XOR swizzle
        for (int task = tid; task < 184 * 8; task += 256) {
            const int r184 = task >> 3, hc = task & 7;
            const int r46 = r184 >> 2, bb = r184 & 3;
            const int t = t0 + r46 - 15;
            f16x8 v = {};
            if (t >= 0 && t < T_)
                v = *(const f16x8*)(Xh + (size_t)(t * 8 + bh * 4 + bb) * C_ +
                                    h * 64 + hc * 8);
            f32x4 lo, hi;
            lo[0] = (float)v[0]; lo[1] = (float)v[1];
            lo[2] = (float)v[2]; lo[3] = (float)v[3];
            hi[0] = (float)v[4]; hi[1] = (float)v[5];
            hi[2] = (float)v[6]; hi[3] = (float)v[7];
            const int sw = r184 & 7;
            *(f32x4*)&xs[r184][((2 * hc) ^ sw) * 4] = lo;
            *(f32x4*)&xs[r184][((2 * hc + 1) ^ sw) * 4] = hi;
        }
        __syncthreads();

        const int bglob = bh * 4 + bl;
        f32x4 cacc[4] = {};
        f32x4 wc[4];
#pragma unroll
        for (int rr = 0; rr < 34; ++rr) {
            const int r184 = (tquad + rr) * 4 + bl;
            const f32x4 xv = *(const f32x4*)&xs[r184][(s ^ (r184 & 7)) * 4];
#pragma unroll
            for (int i = 0; i < 4; ++i) {
                const int k = rr - i;
                if (k < 0 || k > 30) continue;
                if ((k & 3) == 0) {
                    const f16x4 wq = *(const f16x4*)
                        &Wls[(hl * 128 + (tquad + i) * 8 + bglob) * 32 + k];
                    wc[i][0] = (float)wq[0]; wc[i][1] = (float)wq[1];
                    wc[i][2] = (float)wq[2]; wc[i][3] = (float)wq[3];
                }
                cacc[i] += wc[i][k & 3] * xv;
            }
        }
#pragma unroll
        for (int i = 0; i < 4; ++i) {
            const int t = t0 + tquad + i;
            *(f32x4*)(out + (size_t)(t * 8 + bglob) * C_ + h * 64 + s * 4) =
                cacc[i];
        }
    }
}

// ---------------------------------------------------------------------------
extern "C" void kernel_launch(void* const* d_in, const int* in_sizes, int n_in,
                              void* d_out, int out_size, void* d_ws,
                              size_t ws_size, hipStream_t stream) {
    const float* X = (const float*)d_in[0];
    const float* W = (const float*)d_in[1];
    float* out = (float*)d_out;

    // workspace: Wh (1 MiB) | Xh (32 MiB)
    _Float16* Wh = (_Float16*)d_ws;
    _Float16* Xh = (_Float16*)((char*)d_ws + (size_t)NP * C_ * 2);

    cvt_inputs<<<(XCH + WCH) / 256, 256, 0, stream>>>(X, W, Xh, Wh);
    fused_gsc<<<dim3(M_ / 128, NP / 128), 256, 0, stream>>>(Xh, Wh, out);
}